// Round 3
// baseline (1433.867 us; speedup 1.0000x reference)
//
#include <hip/hip_runtime.h>
#include <hip/hip_bf16.h>
#include <math.h>

// Problem constants (fixed by reference)
#define SEQ   3072
#define EMB   1280
#define NHEAD 16
#define HDIM  80
#define QKVN  3840   // 3*EMB
#define NSEGS 3

// ---------------------------------------------------------------------------
// GEMM: C[M][N] = A[M][K] @ B[N][K]^T + bias[N]
// A has row stride lda (so we can read the strided q-slice); B stride = K.
// BM=128, BN=64, BK=32, 256 threads, 8x4 per-thread micro-tile, k-major LDS.
// ---------------------------------------------------------------------------
__device__ __forceinline__ void store_val(float v, float* p)          { *p = v; }
__device__ __forceinline__ void store_val(float v, __hip_bfloat16* p) { *p = __float2bfloat16(v); }

template<typename OT>
__global__ __launch_bounds__(256)
void gemm_nt_bias(const float* __restrict__ A, int lda,
                  const float* __restrict__ B,
                  const float* __restrict__ bias, OT* __restrict__ C,
                  int M, int N, int K)
{
    constexpr int BM = 128, BN = 64, BK = 32;
    __shared__ float As[BK][BM];
    __shared__ float Bs[BK][BN];

    const int tid  = threadIdx.x;
    const int tx   = tid & 15;   // col group: 4 cols each
    const int ty   = tid >> 4;   // row group: 8 rows each
    const int row0 = blockIdx.y * BM;
    const int col0 = blockIdx.x * BN;

    float acc[8][4] = {};

    for (int k0 = 0; k0 < K; k0 += BK) {
        // stage A tile (128 rows x 32 k) -> k-major LDS
        #pragma unroll
        for (int i = 0; i < 4; ++i) {
            int f = tid + i * 256;
            int r = f >> 3, kg = f & 7;
            float4 v = *reinterpret_cast<const float4*>(&A[(size_t)(row0 + r) * lda + k0 + kg * 4]);
            As[kg*4+0][r] = v.x; As[kg*4+1][r] = v.y;
            As[kg*4+2][r] = v.z; As[kg*4+3][r] = v.w;
        }
        // stage B tile (64 rows x 32 k)
        #pragma unroll
        for (int i = 0; i < 2; ++i) {
            int f = tid + i * 256;
            int r = f >> 3, kg = f & 7;
            float4 v = *reinterpret_cast<const float4*>(&B[(size_t)(col0 + r) * K + k0 + kg * 4]);
            Bs[kg*4+0][r] = v.x; Bs[kg*4+1][r] = v.y;
            Bs[kg*4+2][r] = v.z; Bs[kg*4+3][r] = v.w;
        }
        __syncthreads();
        #pragma unroll
        for (int kk = 0; kk < BK; ++kk) {
            float4 a0 = *reinterpret_cast<const float4*>(&As[kk][ty*8]);
            float4 a1 = *reinterpret_cast<const float4*>(&As[kk][ty*8+4]);
            float4 b  = *reinterpret_cast<const float4*>(&Bs[kk][tx*4]);
            float av[8] = {a0.x,a0.y,a0.z,a0.w,a1.x,a1.y,a1.z,a1.w};
            float bv[4] = {b.x,b.y,b.z,b.w};
            #pragma unroll
            for (int r = 0; r < 8; ++r)
                #pragma unroll
                for (int c = 0; c < 4; ++c)
                    acc[r][c] = fmaf(av[r], bv[c], acc[r][c]);
        }
        __syncthreads();
    }

    #pragma unroll
    for (int r = 0; r < 8; ++r) {
        size_t row = (size_t)(row0 + ty*8 + r);
        #pragma unroll
        for (int c = 0; c < 4; ++c) {
            int col = col0 + tx*4 + c;
            store_val(acc[r][c] + bias[col], &C[row * (size_t)N + col]);
        }
    }
}

// ---------------------------------------------------------------------------
// RoPE, in-place on the q and k slices of the qkv buffer.
// One thread per (t in {q,k}, s, h, d<40) rotation pair -> no races.
// ---------------------------------------------------------------------------
__global__ __launch_bounds__(256)
void rope_kernel(float* __restrict__ qkv, const float* __restrict__ rpe)
{
    int idx = blockIdx.x * 256 + threadIdx.x;   // [2][SEQ][NHEAD][40], exact grid
    int d = idx % 40;
    int h = (idx / 40) % NHEAD;
    int s = (idx / (40*NHEAD)) % SEQ;
    int t = idx / (40*NHEAD*SEQ);
    float ang = rpe[s*40 + d];
    float sn = sinf(ang);
    float cs = cosf(ang);
    float* p = qkv + (size_t)s*QKVN + t*EMB + h*HDIM + d;
    float v0 = p[0], v1 = p[40];
    p[0]  = v0*cs - v1*sn;
    p[40] = v1*cs + v0*sn;
}

// ---------------------------------------------------------------------------
// Flash-style attention within each (head, segment). Block = 256 thr handles
// 16 q rows (r = tid>>4) x 16 lanes (g = tid&15). Per 64-key chunk, lane g
// computes scores for keys 4g..4g+3 into Sc[r][.]; after a barrier every
// lane scans its row's 64 scores (LDS broadcast reads) for the running
// max / sum and recomputes p locally for the PV accumulate. Output is
// written IN-PLACE over the q slice.
// ---------------------------------------------------------------------------
__global__ __launch_bounds__(256)
void attn_kernel(float* __restrict__ qkv, const int* __restrict__ cu)
{
    constexpr int KC = 64;
    const int h   = blockIdx.z;
    const int seg = blockIdx.y;
    const int qt  = blockIdx.x;
    const int s0 = cu[seg], s1 = cu[seg+1];

    const int tid = threadIdx.x;
    const int g = tid & 15;
    const int r = tid >> 4;
    const int sq = s0 + qt*16 + r;
    const bool active = sq < s1;

    __shared__ float KsT[HDIM][KC];   // [d][k] transposed: 20 KB
    __shared__ float Vs[KC][HDIM];    // [k][d] row-major:  20 KB
    __shared__ float Sc[16][KC];      // scores per q-row:   4 KB

    // q row in registers, pre-scaled by 1/sqrt(HD)
    float qreg[HDIM];
    {
        const float scale = 0.11180339887498948f;
        const float* qp = qkv + (size_t)(active ? sq : s0) * QKVN + h*HDIM;
        #pragma unroll
        for (int d = 0; d < HDIM; ++d) qreg[d] = qp[d]*scale;
    }

    float m = -3.4e38f, l = 0.f;
    float accA[4] = {0,0,0,0};
    float accB[4] = {0,0,0,0};

    const int quad = tid >> 2;   // 0..63: k-row this thread stages
    const int e    = tid & 3;    // 0..3 : which float4 column group

    for (int kc0 = s0; kc0 < s1; kc0 += KC) {
        __syncthreads();   // previous chunk's LDS reads done
        {
            int kr = kc0 + quad; if (kr > s1-1) kr = s1-1;  // clamp (tail safety)
            const float* krow = qkv + (size_t)kr * QKVN + EMB   + h*HDIM;
            const float* vrow = qkv + (size_t)kr * QKVN + 2*EMB + h*HDIM;
            #pragma unroll
            for (int i = 0; i < 5; ++i) {
                int d4 = e + 4*i;
                float4 kv = *reinterpret_cast<const float4*>(&krow[4*d4]);
                KsT[4*d4+0][quad] = kv.x;
                KsT[4*d4+1][quad] = kv.y;
                KsT[4*d4+2][quad] = kv.z;
                KsT[4*d4+3][quad] = kv.w;
                *reinterpret_cast<float4*>(&Vs[quad][4*d4]) =
                    *reinterpret_cast<const float4*>(&vrow[4*d4]);
            }
        }
        __syncthreads();

        // ---- scores for keys 4g..4g+3 of this chunk ----
        float s4x=0.f, s4y=0.f, s4z=0.f, s4w=0.f;
        #pragma unroll
        for (int d = 0; d < HDIM; ++d) {
            float4 k4 = *reinterpret_cast<const float4*>(&KsT[d][4*g]);
            float qd = qreg[d];
            s4x = fmaf(qd, k4.x, s4x);
            s4y = fmaf(qd, k4.y, s4y);
            s4z = fmaf(qd, k4.z, s4z);
            s4w = fmaf(qd, k4.w, s4w);
        }
        // mask tail keys (no-op for full 1024 segments)
        {
            int kb = kc0 + 4*g;
            if (kb+0 >= s1) s4x = -3.4e38f;
            if (kb+1 >= s1) s4y = -3.4e38f;
            if (kb+2 >= s1) s4z = -3.4e38f;
            if (kb+3 >= s1) s4w = -3.4e38f;
        }
        Sc[r][4*g+0] = s4x;
        Sc[r][4*g+1] = s4y;
        Sc[r][4*g+2] = s4z;
        Sc[r][4*g+3] = s4w;
        __syncthreads();

        // ---- online softmax: every lane scans its row (broadcast reads) ----
        float mloc = -3.4e38f;
        #pragma unroll
        for (int kk = 0; kk < KC; ++kk) mloc = fmaxf(mloc, Sc[r][kk]);
        float mnew = fmaxf(m, mloc);
        float corr = __expf(m - mnew);
        l *= corr;
        #pragma unroll
        for (int j = 0; j < 4; ++j) { accA[j] *= corr; accB[j] *= corr; }

        #pragma unroll 8
        for (int kk = 0; kk < KC; ++kk) {
            float p = __expf(Sc[r][kk] - mnew);
            l += p;
            const float4 v4 = *reinterpret_cast<const float4*>(&Vs[kk][4*g]);
            accA[0] = fmaf(p, v4.x, accA[0]);
            accA[1] = fmaf(p, v4.y, accA[1]);
            accA[2] = fmaf(p, v4.z, accA[2]);
            accA[3] = fmaf(p, v4.w, accA[3]);
            if (g < 4) {
                const float4 v4b = *reinterpret_cast<const float4*>(&Vs[kk][64 + 4*g]);
                accB[0] = fmaf(p, v4b.x, accB[0]);
                accB[1] = fmaf(p, v4b.y, accB[1]);
                accB[2] = fmaf(p, v4b.z, accB[2]);
                accB[3] = fmaf(p, v4b.w, accB[3]);
            }
        }
        m = mnew;
    }

    if (active) {
        float inv = 1.f / l;
        float* op = qkv + (size_t)sq * QKVN + h*HDIM;   // overwrite q slice
        float4 oa = {accA[0]*inv, accA[1]*inv, accA[2]*inv, accA[3]*inv};
        *reinterpret_cast<float4*>(&op[4*g]) = oa;
        if (g < 4) {
            float4 ob = {accB[0]*inv, accB[1]*inv, accB[2]*inv, accB[3]*inv};
            *reinterpret_cast<float4*>(&op[64 + 4*g]) = ob;
        }
    }
}

// ---------------------------------------------------------------------------
extern "C" void kernel_launch(void* const* d_in, const int* in_sizes, int n_in,
                              void* d_out, int out_size, void* d_ws, size_t ws_size,
                              hipStream_t stream)
{
    const float* x      = (const float*)d_in[0];
    const float* rpe    = (const float*)d_in[1];
    const float* qkv_w  = (const float*)d_in[2];
    const float* qkv_b  = (const float*)d_in[3];
    const float* proj_w = (const float*)d_in[4];
    const float* proj_b = (const float*)d_in[5];
    const int*   cu     = (const int*)d_in[6];
    float* out = (float*)d_out;     // reference output dtype is float32

    float* qkv_ws = (float*)d_ws;    // 3072*3840 f32 = 47.2 MB (ONLY ws use)

    dim3 blk(256);

    // 1) qkv = x @ qkv_w^T + qkv_b
    gemm_nt_bias<float><<<dim3(QKVN/64, SEQ/128), blk, 0, stream>>>(
        x, EMB, qkv_w, qkv_b, qkv_ws, SEQ, QKVN, EMB);

    // 2) RoPE in-place on q,k
    int rope_threads = 2 * SEQ * NHEAD * (HDIM/2);       // 3,932,160 (exact /256)
    rope_kernel<<<dim3(rope_threads/256), blk, 0, stream>>>(qkv_ws, rpe);

    // 3) block-diagonal attention; output overwrites the q slice
    attn_kernel<<<dim3((SEQ/NSEGS)/16, NSEGS, NHEAD), blk, 0, stream>>>(
        qkv_ws, cu);

    // 4) out = attn @ proj_w^T + proj_b  (A = q slice, lda = 3840; f32 store)
    gemm_nt_bias<float><<<dim3(EMB/64, SEQ/128), blk, 0, stream>>>(
        qkv_ws, QKVN, proj_w, proj_b, out, SEQ, EMB, EMB);
}

// Round 4
// 699.143 us; speedup vs baseline: 2.0509x; 2.0509x over previous
//
#include <hip/hip_runtime.h>
#include <hip/hip_bf16.h>
#include <math.h>

// Problem constants (fixed by reference)
#define SEQ   3072
#define EMB   1280
#define NHEAD 16
#define HDIM  80
#define QKVN  3840   // 3*EMB
#define NSEGS 3

typedef __attribute__((ext_vector_type(8))) short bf16x8;  // 8 bf16 (4 VGPRs)
typedef __attribute__((ext_vector_type(4))) float f32x4;   // MFMA C/D frag

__device__ __forceinline__ short f2bf(float f) {
    __hip_bfloat16 h = __float2bfloat16(f);
    return *reinterpret_cast<short*>(&h);
}

// ---------------------------------------------------------------------------
// GEMM: C[M][N] = A[M][K] @ B[N][K]^T + bias[N]   (unchanged from round 3)
// ---------------------------------------------------------------------------
__device__ __forceinline__ void store_val(float v, float* p)          { *p = v; }
__device__ __forceinline__ void store_val(float v, __hip_bfloat16* p) { *p = __float2bfloat16(v); }

template<typename OT>
__global__ __launch_bounds__(256)
void gemm_nt_bias(const float* __restrict__ A, int lda,
                  const float* __restrict__ B,
                  const float* __restrict__ bias, OT* __restrict__ C,
                  int M, int N, int K)
{
    constexpr int BM = 128, BN = 64, BK = 32;
    __shared__ float As[BK][BM];
    __shared__ float Bs[BK][BN];

    const int tid  = threadIdx.x;
    const int tx   = tid & 15;
    const int ty   = tid >> 4;
    const int row0 = blockIdx.y * BM;
    const int col0 = blockIdx.x * BN;

    float acc[8][4] = {};

    for (int k0 = 0; k0 < K; k0 += BK) {
        #pragma unroll
        for (int i = 0; i < 4; ++i) {
            int f = tid + i * 256;
            int r = f >> 3, kg = f & 7;
            float4 v = *reinterpret_cast<const float4*>(&A[(size_t)(row0 + r) * lda + k0 + kg * 4]);
            As[kg*4+0][r] = v.x; As[kg*4+1][r] = v.y;
            As[kg*4+2][r] = v.z; As[kg*4+3][r] = v.w;
        }
        #pragma unroll
        for (int i = 0; i < 2; ++i) {
            int f = tid + i * 256;
            int r = f >> 3, kg = f & 7;
            float4 v = *reinterpret_cast<const float4*>(&B[(size_t)(col0 + r) * K + k0 + kg * 4]);
            Bs[kg*4+0][r] = v.x; Bs[kg*4+1][r] = v.y;
            Bs[kg*4+2][r] = v.z; Bs[kg*4+3][r] = v.w;
        }
        __syncthreads();
        #pragma unroll
        for (int kk = 0; kk < BK; ++kk) {
            float4 a0 = *reinterpret_cast<const float4*>(&As[kk][ty*8]);
            float4 a1 = *reinterpret_cast<const float4*>(&As[kk][ty*8+4]);
            float4 b  = *reinterpret_cast<const float4*>(&Bs[kk][tx*4]);
            float av[8] = {a0.x,a0.y,a0.z,a0.w,a1.x,a1.y,a1.z,a1.w};
            float bv[4] = {b.x,b.y,b.z,b.w};
            #pragma unroll
            for (int r = 0; r < 8; ++r)
                #pragma unroll
                for (int c = 0; c < 4; ++c)
                    acc[r][c] = fmaf(av[r], bv[c], acc[r][c]);
        }
        __syncthreads();
    }

    #pragma unroll
    for (int r = 0; r < 8; ++r) {
        size_t row = (size_t)(row0 + ty*8 + r);
        #pragma unroll
        for (int c = 0; c < 4; ++c) {
            int col = col0 + tx*4 + c;
            store_val(acc[r][c] + bias[col], &C[row * (size_t)N + col]);
        }
    }
}

// ---------------------------------------------------------------------------
// RoPE, in-place on q and k slices (unchanged from round 3)
// ---------------------------------------------------------------------------
__global__ __launch_bounds__(256)
void rope_kernel(float* __restrict__ qkv, const float* __restrict__ rpe)
{
    int idx = blockIdx.x * 256 + threadIdx.x;
    int d = idx % 40;
    int h = (idx / 40) % NHEAD;
    int s = (idx / (40*NHEAD)) % SEQ;
    int t = idx / (40*NHEAD*SEQ);
    float ang = rpe[s*40 + d];
    float sn = sinf(ang);
    float cs = cosf(ang);
    float* p = qkv + (size_t)s*QKVN + t*EMB + h*HDIM + d;
    float v0 = p[0], v1 = p[40];
    p[0]  = v0*cs - v1*sn;
    p[40] = v1*cs + v0*sn;
}

// ---------------------------------------------------------------------------
// MFMA flash attention. Block = 4 waves = 64 q rows of one (head, seg).
// mfma_f32_16x16x32_bf16 layouts (verified, guide §3):
//   A: row = lane&15,  k  = (lane>>4)*8 + j   (8 contiguous k per lane)
//   B: col = lane&15,  k  = (lane>>4)*8 + j
//   C/D: col = lane&15, row = (lane>>4)*4 + reg
// Q in regs (3 A-frags, d padded to 96 with zeros). K in LDS row-major bf16
// [64][128] with XOR-swizzled 8-elem units (avoids 8-way read conflicts).
// V transposed into Vt[80][64] (same swizzle). P written per-wave to a
// swizzled [16][64] bf16 tile and re-read as A-frags. Softmax in-register,
// reductions via width-16 shfl_xor. Assumes segment lengths are multiples
// of 64 (true for this problem: all segs = 1024). Output overwrites q slice.
// ---------------------------------------------------------------------------
__global__ __launch_bounds__(256)
void attn_mfma(float* __restrict__ qkv, const int* __restrict__ cu)
{
    const int h   = blockIdx.z;
    const int seg = blockIdx.y;
    const int qt  = blockIdx.x;
    const int s0 = cu[seg], s1 = cu[seg+1];

    const int tid = threadIdx.x;
    const int w   = tid >> 6;      // wave 0..3
    const int l   = tid & 63;
    const int l15 = l & 15;
    const int l4  = l >> 4;        // 0..3

    __shared__ short Kl[64][128];    // 16 KB: K rows, swizzled units of 8 bf16
    __shared__ short Vt[HDIM][64];   // 10 KB: V^T, swizzled units
    __shared__ short Pl[4][16][64];  //  8 KB: per-wave P tiles, swizzled

    const int q0   = s0 + qt*64 + w*16;   // wave's q-row base
    const int qrow = q0 + l15;

    // ---- Q fragments (A-operand), pre-scaled, bf16, d padded to 96 ----
    bf16x8 qf[3];
    {
        const float scale = 0.11180339887498948f;   // 1/sqrt(80)
        const float* qp = qkv + (size_t)qrow * QKVN + h*HDIM;
        #pragma unroll
        for (int t = 0; t < 3; ++t) {
            #pragma unroll
            for (int j = 0; j < 8; ++j) {
                int d = t*32 + l4*8 + j;
                qf[t][j] = (d < HDIM) ? f2bf(qp[d]*scale) : (short)0;
            }
        }
    }

    float m[4], lsum[4];
    f32x4 O[5];
    #pragma unroll
    for (int r = 0; r < 4; ++r) { m[r] = -3.4e38f; lsum[r] = 0.f; }
    #pragma unroll
    for (int d = 0; d < 5; ++d) O[d] = (f32x4){0.f,0.f,0.f,0.f};

    const int nk = s1 - s0;
    for (int kc = 0; kc < nk; kc += 64) {
        __syncthreads();   // previous chunk's LDS reads complete

        // ---- stage K chunk: 64 rows x 12 units (units 10,11 = zero pad) ----
        #pragma unroll
        for (int i = 0; i < 3; ++i) {
            int task = tid + i*256;          // 768 = 64*12
            int key  = task / 12;
            int u    = task - key*12;
            bf16x8 t;
            if (u < 10) {
                const float* kp = qkv + (size_t)(s0 + kc + key)*QKVN + EMB + h*HDIM + u*8;
                #pragma unroll
                for (int j = 0; j < 8; ++j) t[j] = f2bf(kp[j]);
            } else {
                #pragma unroll
                for (int j = 0; j < 8; ++j) t[j] = 0;
            }
            *reinterpret_cast<bf16x8*>(&Kl[key][(u ^ (key & 7))*8]) = t;
        }
        // ---- stage V transposed: 64 k x 20 d-quads ----
        #pragma unroll
        for (int i = 0; i < 5; ++i) {
            int task = tid + i*256;          // 1280 = 64*20
            int k  = task / 20;
            int dq = task - k*20;
            const float* vp = qkv + (size_t)(s0 + kc + k)*QKVN + 2*EMB + h*HDIM + dq*4;
            float4 v4 = *reinterpret_cast<const float4*>(vp);
            int d0 = dq*4;
            Vt[d0+0][(((k>>3) ^ ((d0+0)&7))*8) + (k&7)] = f2bf(v4.x);
            Vt[d0+1][(((k>>3) ^ ((d0+1)&7))*8) + (k&7)] = f2bf(v4.y);
            Vt[d0+2][(((k>>3) ^ ((d0+2)&7))*8) + (k&7)] = f2bf(v4.z);
            Vt[d0+3][(((k>>3) ^ ((d0+3)&7))*8) + (k&7)] = f2bf(v4.w);
        }
        __syncthreads();

        // ---- S = Q K^T  (4 col-tiles x 3 k-steps) ----
        f32x4 S[4];
        #pragma unroll
        for (int ct = 0; ct < 4; ++ct) {
            f32x4 acc = {0.f,0.f,0.f,0.f};
            int key = ct*16 + l15;
            #pragma unroll
            for (int t = 0; t < 3; ++t) {
                int u = (4*t + l4) ^ (key & 7);
                bf16x8 b = *reinterpret_cast<const bf16x8*>(&Kl[key][u*8]);
                acc = __builtin_amdgcn_mfma_f32_16x16x32_bf16(qf[t], b, acc, 0, 0, 0);
            }
            S[ct] = acc;
        }

        // ---- online softmax on D-frag rows; write P tile (bf16) ----
        #pragma unroll
        for (int r = 0; r < 4; ++r) {
            float mx = fmaxf(fmaxf(S[0][r], S[1][r]), fmaxf(S[2][r], S[3][r]));
            #pragma unroll
            for (int o = 8; o >= 1; o >>= 1) mx = fmaxf(mx, __shfl_xor(mx, o, 16));
            float mn   = fmaxf(m[r], mx);
            float corr = __expf(m[r] - mn);
            float p0 = __expf(S[0][r] - mn);
            float p1 = __expf(S[1][r] - mn);
            float p2 = __expf(S[2][r] - mn);
            float p3 = __expf(S[3][r] - mn);
            float ps = p0 + p1 + p2 + p3;
            #pragma unroll
            for (int o = 8; o >= 1; o >>= 1) ps += __shfl_xor(ps, o, 16);
            lsum[r] = lsum[r]*corr + ps;
            m[r] = mn;
            #pragma unroll
            for (int d = 0; d < 5; ++d) O[d][r] *= corr;

            int row = l4*4 + r;                 // P row this lane owns
            int cu8 = l15 >> 3, c7 = l15 & 7;   // col unit offset / in-unit pos
            short* prow = &Pl[w][row][0];
            prow[((0 + cu8) ^ (row & 7))*8 + c7] = f2bf(p0);
            prow[((2 + cu8) ^ (row & 7))*8 + c7] = f2bf(p1);
            prow[((4 + cu8) ^ (row & 7))*8 + c7] = f2bf(p2);
            prow[((6 + cu8) ^ (row & 7))*8 + c7] = f2bf(p3);
        }

        // ---- O += P V  (2 k-steps x 5 d-tiles) ----
        #pragma unroll
        for (int kq = 0; kq < 2; ++kq) {
            int pu = (kq*4 + l4) ^ (l15 & 7);
            bf16x8 a = *reinterpret_cast<const bf16x8*>(&Pl[w][l15][pu*8]);
            #pragma unroll
            for (int dt = 0; dt < 5; ++dt) {
                int d  = dt*16 + l15;
                int vu = (kq*4 + l4) ^ (d & 7);
                bf16x8 b = *reinterpret_cast<const bf16x8*>(&Vt[d][vu*8]);
                O[dt] = __builtin_amdgcn_mfma_f32_16x16x32_bf16(a, b, O[dt], 0, 0, 0);
            }
        }
    }

    // ---- normalize and write over the q slice ----
    #pragma unroll
    for (int r = 0; r < 4; ++r) {
        float inv = 1.f / lsum[r];
        float* op = qkv + (size_t)(q0 + l4*4 + r) * QKVN + h*HDIM;
        #pragma unroll
        for (int dt = 0; dt < 5; ++dt)
            op[dt*16 + l15] = O[dt][r] * inv;
    }
}

// ---------------------------------------------------------------------------
extern "C" void kernel_launch(void* const* d_in, const int* in_sizes, int n_in,
                              void* d_out, int out_size, void* d_ws, size_t ws_size,
                              hipStream_t stream)
{
    const float* x      = (const float*)d_in[0];
    const float* rpe    = (const float*)d_in[1];
    const float* qkv_w  = (const float*)d_in[2];
    const float* qkv_b  = (const float*)d_in[3];
    const float* proj_w = (const float*)d_in[4];
    const float* proj_b = (const float*)d_in[5];
    const int*   cu     = (const int*)d_in[6];
    float* out = (float*)d_out;

    float* qkv_ws = (float*)d_ws;    // 3072*3840 f32 = 47.2 MB (only ws use)

    dim3 blk(256);

    // 1) qkv = x @ qkv_w^T + qkv_b
    gemm_nt_bias<float><<<dim3(QKVN/64, SEQ/128), blk, 0, stream>>>(
        x, EMB, qkv_w, qkv_b, qkv_ws, SEQ, QKVN, EMB);

    // 2) RoPE in-place on q,k
    int rope_threads = 2 * SEQ * NHEAD * (HDIM/2);
    rope_kernel<<<dim3(rope_threads/256), blk, 0, stream>>>(qkv_ws, rpe);

    // 3) block-diagonal MFMA attention; output overwrites q slice
    attn_mfma<<<dim3((SEQ/NSEGS)/64, NSEGS, NHEAD), blk, 0, stream>>>(
        qkv_ws, cu);

    // 4) out = attn @ proj_w^T + proj_b
    gemm_nt_bias<float><<<dim3(EMB/64, SEQ/128), blk, 0, stream>>>(
        qkv_ws, QKVN, proj_w, proj_b, out, SEQ, EMB, EMB);
}

// Round 5
// 230.843 us; speedup vs baseline: 6.2114x; 3.0286x over previous
//
#include <hip/hip_runtime.h>
#include <hip/hip_bf16.h>
#include <math.h>

// Problem constants (fixed by reference)
#define SEQ   3072
#define EMB   1280
#define NHEAD 16
#define HDIM  80
#define QKVN  3840   // 3*EMB
#define NSEGS 3

typedef __attribute__((ext_vector_type(8))) short bf16x8;  // 8 bf16 (4 VGPRs)
typedef __attribute__((ext_vector_type(4))) short short4v;
typedef __attribute__((ext_vector_type(4))) float f32x4;   // MFMA C/D frag

__device__ __forceinline__ short f2bf(float f) {
    __hip_bfloat16 h = __float2bfloat16(f);
    return *reinterpret_cast<short*>(&h);
}
__device__ __forceinline__ float bf2f(short s) {
    unsigned int u = ((unsigned int)(unsigned short)s) << 16;
    union { unsigned int u; float f; } c; c.u = u;
    return c.f;
}

// async global->LDS, 16 B per lane; LDS dest = wave-uniform base + lane*16
__device__ __forceinline__ void gload_lds16(const void* g, void* l) {
    __builtin_amdgcn_global_load_lds(
        (const __attribute__((address_space(1))) unsigned int*)g,
        (__attribute__((address_space(3))) unsigned int*)l, 16, 0, 0);
}

// ---------------------------------------------------------------------------
// f32 -> bf16 conversion (vectorized: 8 elems / thread)
// ---------------------------------------------------------------------------
__global__ __launch_bounds__(256)
void cvt_bf16_kernel(const float* __restrict__ in, short* __restrict__ out, int n8)
{
    int i = blockIdx.x * 256 + threadIdx.x;
    if (i >= n8) return;
    float4 a = *reinterpret_cast<const float4*>(&in[i*8]);
    float4 b = *reinterpret_cast<const float4*>(&in[i*8+4]);
    bf16x8 o;
    o[0]=f2bf(a.x); o[1]=f2bf(a.y); o[2]=f2bf(a.z); o[3]=f2bf(a.w);
    o[4]=f2bf(b.x); o[5]=f2bf(b.y); o[6]=f2bf(b.z); o[7]=f2bf(b.w);
    *reinterpret_cast<bf16x8*>(&out[i*8]) = o;
}

// ---------------------------------------------------------------------------
// bf16 MFMA GEMM: C[M][N] = A[M][K] @ B[N][K]^T + bias[N]
// A row stride lda, B row stride K (both bf16). m97-structure: 128x128 tile,
// BK=32, 4 waves (2x2), 4x4 16x16x32 frags/wave, global_load_lds staging,
// single-buffered 2-barrier K-loop. LDS rows are 64 B -> frag ds_read_b128
// loads all 32 banks uniformly (no swizzle needed, linear DMA dest works).
// ---------------------------------------------------------------------------
__device__ __forceinline__ void store_val(float v, float* p) { *p = v; }
__device__ __forceinline__ void store_val(float v, short* p) { *p = f2bf(v); }

template<typename OT>
__global__ __launch_bounds__(256)
void gemm_bf16_nt(const short* __restrict__ A, int lda,
                  const short* __restrict__ B,
                  const float* __restrict__ bias, OT* __restrict__ C,
                  int M, int N, int K)
{
    __shared__ short As[128][32];   // 8 KB
    __shared__ short Bs[128][32];   // 8 KB

    const int tid = threadIdx.x;
    const int w   = tid >> 6;       // wave 0..3
    const int l   = tid & 63;
    const int l15 = l & 15;
    const int l4  = l >> 4;
    const int wr  = w >> 1;         // wave row (2x2 grid)
    const int wc  = w & 1;
    const int row0 = blockIdx.y * 128;
    const int col0 = blockIdx.x * 128;

    // staging geometry: chunk = 16 rows (1 KB); lane -> row c*16 + l/4, unit l%4
    const int srow = l >> 2;
    const int sk   = (l & 3) * 8;

    f32x4 acc[4][4];
    #pragma unroll
    for (int mi = 0; mi < 4; ++mi)
        #pragma unroll
        for (int ni = 0; ni < 4; ++ni) acc[mi][ni] = (f32x4){0.f,0.f,0.f,0.f};

    for (int k0 = 0; k0 < K; k0 += 32) {
        // wave w stages chunks w and w+4 of each tile (4 DMA instrs / wave)
        {
            const int c0 = w, c1 = w + 4;
            gload_lds16(&A[(size_t)(row0 + c0*16 + srow) * lda + k0 + sk], &As[c0*16][0]);
            gload_lds16(&A[(size_t)(row0 + c1*16 + srow) * lda + k0 + sk], &As[c1*16][0]);
            gload_lds16(&B[(size_t)(col0 + c0*16 + srow) * K   + k0 + sk], &Bs[c0*16][0]);
            gload_lds16(&B[(size_t)(col0 + c1*16 + srow) * K   + k0 + sk], &Bs[c1*16][0]);
        }
        __syncthreads();   // drains DMA (compiler emits vmcnt(0) before barrier)

        bf16x8 af[4], bfr[4];
        #pragma unroll
        for (int mi = 0; mi < 4; ++mi)
            af[mi] = *reinterpret_cast<const bf16x8*>(&As[wr*64 + mi*16 + l15][l4*8]);
        #pragma unroll
        for (int ni = 0; ni < 4; ++ni)
            bfr[ni] = *reinterpret_cast<const bf16x8*>(&Bs[wc*64 + ni*16 + l15][l4*8]);

        #pragma unroll
        for (int mi = 0; mi < 4; ++mi)
            #pragma unroll
            for (int ni = 0; ni < 4; ++ni)
                acc[mi][ni] = __builtin_amdgcn_mfma_f32_16x16x32_bf16(
                    af[mi], bfr[ni], acc[mi][ni], 0, 0, 0);
        __syncthreads();   // LDS reads done before next DMA overwrites
    }

    // epilogue: C/D frag layout col=l15, row=l4*4+r
    #pragma unroll
    for (int ni = 0; ni < 4; ++ni) {
        int col = col0 + wc*64 + ni*16 + l15;
        float bv = bias[col];
        #pragma unroll
        for (int mi = 0; mi < 4; ++mi) {
            #pragma unroll
            for (int r = 0; r < 4; ++r) {
                size_t row = (size_t)(row0 + wr*64 + mi*16 + l4*4 + r);
                store_val(acc[mi][ni][r] + bv, &C[row * (size_t)N + col]);
            }
        }
    }
}

// ---------------------------------------------------------------------------
// RoPE in-place on bf16 q,k slices. Thread handles 8 rotation pairs
// (vectorized bf16x8 loads/stores). Grid exact: 2*SEQ*NHEAD*5 / 256.
// ---------------------------------------------------------------------------
__global__ __launch_bounds__(256)
void rope_bf16_kernel(short* __restrict__ qkv, const float* __restrict__ rpe)
{
    int idx = blockIdx.x * 256 + threadIdx.x;   // [t][s][h][blk], blk<5
    int blk = idx % 5;
    int h   = (idx / 5) % NHEAD;
    int s   = (idx / (5*NHEAD)) % SEQ;
    int t   = idx / (5*NHEAD*SEQ);
    int d0  = blk * 8;

    const float* rp = rpe + s*40 + d0;
    short* p = qkv + (size_t)s*QKVN + t*EMB + h*HDIM + d0;
    bf16x8 v0 = *reinterpret_cast<const bf16x8*>(p);
    bf16x8 v1 = *reinterpret_cast<const bf16x8*>(p + 40);
    bf16x8 o0, o1;
    #pragma unroll
    for (int j = 0; j < 8; ++j) {
        float ang = rp[j];
        float sn = sinf(ang), cs = cosf(ang);
        float a = bf2f(v0[j]), b = bf2f(v1[j]);
        o0[j] = f2bf(a*cs - b*sn);
        o1[j] = f2bf(b*cs + a*sn);
    }
    *reinterpret_cast<bf16x8*>(p)      = o0;
    *reinterpret_cast<bf16x8*>(p + 40) = o1;
}

// ---------------------------------------------------------------------------
// MFMA flash attention on bf16 qkv. Block = 4 waves = 64 q rows of one
// (head, seg). Same structure as round 4 (verified layouts), but: inputs are
// already bf16 (staging = raw 16 B copies), 1/sqrt(80) folded into f32
// logits post-MFMA, output written bf16 to a planar [SEQ][EMB] buffer.
// ---------------------------------------------------------------------------
__global__ __launch_bounds__(256)
void attn_mfma(const short* __restrict__ qkv, const int* __restrict__ cu,
               short* __restrict__ aout)
{
    const int h   = blockIdx.z;
    const int seg = blockIdx.y;
    const int qt  = blockIdx.x;
    const int s0 = cu[seg], s1 = cu[seg+1];

    const int tid = threadIdx.x;
    const int w   = tid >> 6;
    const int l   = tid & 63;
    const int l15 = l & 15;
    const int l4  = l >> 4;

    __shared__ short Kl[64][128];    // 16 KB, XOR-swizzled 8-elem units
    __shared__ short Vt[HDIM][64];   // 10 KB, V^T swizzled
    __shared__ short Pl[4][16][64];  //  8 KB, per-wave P tiles

    const int q0   = s0 + qt*64 + w*16;
    const int qrow = q0 + l15;

    bf16x8 bzero;
    #pragma unroll
    for (int j = 0; j < 8; ++j) bzero[j] = 0;

    // Q fragments (raw bf16, no scaling; d padded 80->96)
    bf16x8 qf[3];
    {
        const short* qp = qkv + (size_t)qrow * QKVN + h*HDIM;
        qf[0] = *reinterpret_cast<const bf16x8*>(qp + l4*8);
        qf[1] = *reinterpret_cast<const bf16x8*>(qp + 32 + l4*8);
        qf[2] = (l4 < 2) ? *reinterpret_cast<const bf16x8*>(qp + 64 + l4*8) : bzero;
    }

    float m[4], lsum[4];
    f32x4 O[5];
    #pragma unroll
    for (int r = 0; r < 4; ++r) { m[r] = -3.4e38f; lsum[r] = 0.f; }
    #pragma unroll
    for (int d = 0; d < 5; ++d) O[d] = (f32x4){0.f,0.f,0.f,0.f};

    const float scale = 0.11180339887498948f;   // 1/sqrt(80)
    const int nk = s1 - s0;

    for (int kc = 0; kc < nk; kc += 64) {
        __syncthreads();

        // stage K chunk: 64 rows x 12 units (units 10,11 zero-pad)
        #pragma unroll
        for (int i = 0; i < 3; ++i) {
            int task = tid + i*256;
            int key  = task / 12;
            int u    = task - key*12;
            bf16x8 t = (u < 10)
                ? *reinterpret_cast<const bf16x8*>(qkv + (size_t)(s0+kc+key)*QKVN + EMB + h*HDIM + u*8)
                : bzero;
            *reinterpret_cast<bf16x8*>(&Kl[key][(u ^ (key & 7))*8]) = t;
        }
        // stage V transposed: 64 k x 20 d-quads
        #pragma unroll
        for (int i = 0; i < 5; ++i) {
            int task = tid + i*256;
            int k  = task / 20;
            int dq = task - k*20;
            short4v v4 = *reinterpret_cast<const short4v*>(
                qkv + (size_t)(s0+kc+k)*QKVN + 2*EMB + h*HDIM + dq*4);
            int d0 = dq*4;
            Vt[d0+0][(((k>>3) ^ ((d0+0)&7))*8) + (k&7)] = v4[0];
            Vt[d0+1][(((k>>3) ^ ((d0+1)&7))*8) + (k&7)] = v4[1];
            Vt[d0+2][(((k>>3) ^ ((d0+2)&7))*8) + (k&7)] = v4[2];
            Vt[d0+3][(((k>>3) ^ ((d0+3)&7))*8) + (k&7)] = v4[3];
        }
        __syncthreads();

        // S = Q K^T (4 col-tiles x 3 k-steps), then scale in f32
        f32x4 S[4];
        #pragma unroll
        for (int ct = 0; ct < 4; ++ct) {
            f32x4 acc = (f32x4){0.f,0.f,0.f,0.f};
            int key = ct*16 + l15;
            #pragma unroll
            for (int t = 0; t < 3; ++t) {
                int u = (4*t + l4) ^ (key & 7);
                bf16x8 b = *reinterpret_cast<const bf16x8*>(&Kl[key][u*8]);
                acc = __builtin_amdgcn_mfma_f32_16x16x32_bf16(qf[t], b, acc, 0, 0, 0);
            }
            #pragma unroll
            for (int r = 0; r < 4; ++r) acc[r] *= scale;
            S[ct] = acc;
        }

        // online softmax on D-frag rows; write P tile (bf16)
        #pragma unroll
        for (int r = 0; r < 4; ++r) {
            float mx = fmaxf(fmaxf(S[0][r], S[1][r]), fmaxf(S[2][r], S[3][r]));
            #pragma unroll
            for (int o = 8; o >= 1; o >>= 1) mx = fmaxf(mx, __shfl_xor(mx, o, 16));
            float mn   = fmaxf(m[r], mx);
            float corr = __expf(m[r] - mn);
            float p0 = __expf(S[0][r] - mn);
            float p1 = __expf(S[1][r] - mn);
            float p2 = __expf(S[2][r] - mn);
            float p3 = __expf(S[3][r] - mn);
            float ps = p0 + p1 + p2 + p3;
            #pragma unroll
            for (int o = 8; o >= 1; o >>= 1) ps += __shfl_xor(ps, o, 16);
            lsum[r] = lsum[r]*corr + ps;
            m[r] = mn;
            #pragma unroll
            for (int d = 0; d < 5; ++d) O[d][r] *= corr;

            int row = l4*4 + r;
            int cu8 = l15 >> 3, c7 = l15 & 7;
            short* prow = &Pl[w][row][0];
            prow[((0 + cu8) ^ (row & 7))*8 + c7] = f2bf(p0);
            prow[((2 + cu8) ^ (row & 7))*8 + c7] = f2bf(p1);
            prow[((4 + cu8) ^ (row & 7))*8 + c7] = f2bf(p2);
            prow[((6 + cu8) ^ (row & 7))*8 + c7] = f2bf(p3);
        }

        // O += P V (2 k-steps x 5 d-tiles)
        #pragma unroll
        for (int kq = 0; kq < 2; ++kq) {
            int pu = (kq*4 + l4) ^ (l15 & 7);
            bf16x8 a = *reinterpret_cast<const bf16x8*>(&Pl[w][l15][pu*8]);
            #pragma unroll
            for (int dt = 0; dt < 5; ++dt) {
                int d  = dt*16 + l15;
                int vu = (kq*4 + l4) ^ (d & 7);
                bf16x8 b = *reinterpret_cast<const bf16x8*>(&Vt[d][vu*8]);
                O[dt] = __builtin_amdgcn_mfma_f32_16x16x32_bf16(a, b, O[dt], 0, 0, 0);
            }
        }
    }

    // normalize, write bf16 to planar attn-out [SEQ][EMB]
    #pragma unroll
    for (int r = 0; r < 4; ++r) {
        float inv = 1.f / lsum[r];
        short* op = aout + (size_t)(q0 + l4*4 + r) * EMB + h*HDIM;
        #pragma unroll
        for (int dt = 0; dt < 5; ++dt)
            op[dt*16 + l15] = f2bf(O[dt][r] * inv);
    }
}

// ---------------------------------------------------------------------------
extern "C" void kernel_launch(void* const* d_in, const int* in_sizes, int n_in,
                              void* d_out, int out_size, void* d_ws, size_t ws_size,
                              hipStream_t stream)
{
    const float* x      = (const float*)d_in[0];
    const float* rpe    = (const float*)d_in[1];
    const float* qkv_w  = (const float*)d_in[2];
    const float* qkv_b  = (const float*)d_in[3];
    const float* proj_w = (const float*)d_in[4];
    const float* proj_b = (const float*)d_in[5];
    const int*   cu     = (const int*)d_in[6];
    float* out = (float*)d_out;

    // workspace (bf16 shorts), 52.4 MB total
    short* ws       = (short*)d_ws;
    short* qkv_bf   = ws;                                   // SEQ*QKVN
    short* x_bf     = qkv_bf  + (size_t)SEQ * QKVN;         // SEQ*EMB
    short* qkvw_bf  = x_bf    + (size_t)SEQ * EMB;          // QKVN*EMB
    short* projw_bf = qkvw_bf + (size_t)QKVN * EMB;         // EMB*EMB
    short* attn_bf  = projw_bf+ (size_t)EMB * EMB;          // SEQ*EMB

    dim3 blk(256);

    // 0) convert inputs to bf16 (exact grids, all sizes % 2048 == 0)
    cvt_bf16_kernel<<<dim3(SEQ*EMB/8/256),  blk, 0, stream>>>(x,      x_bf,     SEQ*EMB/8);
    cvt_bf16_kernel<<<dim3(QKVN*EMB/8/256), blk, 0, stream>>>(qkv_w,  qkvw_bf,  QKVN*EMB/8);
    cvt_bf16_kernel<<<dim3(EMB*EMB/8/256),  blk, 0, stream>>>(proj_w, projw_bf, EMB*EMB/8);

    // 1) qkv = x @ qkv_w^T + qkv_b  (bf16 out)
    gemm_bf16_nt<short><<<dim3(QKVN/128, SEQ/128), blk, 0, stream>>>(
        x_bf, EMB, qkvw_bf, qkv_b, qkv_bf, SEQ, QKVN, EMB);

    // 2) RoPE in-place on bf16 q,k
    gemm_bf16_nt<short>; // (no-op expr removed by compiler)  // keep layout stable
    rope_bf16_kernel<<<dim3(2*SEQ*NHEAD*5/256), blk, 0, stream>>>(qkv_bf, rpe);

    // 3) block-diagonal MFMA attention -> bf16 planar attn_bf
    attn_mfma<<<dim3((SEQ/NSEGS)/64, NSEGS, NHEAD), blk, 0, stream>>>(
        qkv_bf, cu, attn_bf);

    // 4) out = attn @ proj_w^T + proj_b (f32 out)
    gemm_bf16_nt<float><<<dim3(EMB/128, SEQ/128), blk, 0, stream>>>(
        attn_bf, EMB, projw_bf, proj_b, out, SEQ, EMB, EMB);
}

// Round 6
// 178.954 us; speedup vs baseline: 8.0125x; 1.2900x over previous
//
#include <hip/hip_runtime.h>
#include <hip/hip_bf16.h>
#include <math.h>

// Problem constants (fixed by reference)
#define SEQ   3072
#define EMB   1280
#define NHEAD 16
#define HDIM  80
#define QKVN  3840   // 3*EMB
#define NSEGS 3

typedef __attribute__((ext_vector_type(8))) short bf16x8;  // 8 bf16 (4 VGPRs)
typedef __attribute__((ext_vector_type(4))) short bf16x4;  // 4 bf16 (8 B)
typedef __attribute__((ext_vector_type(4))) float f32x4;   // MFMA C/D frag

__device__ __forceinline__ short f2bf(float f) {
    __hip_bfloat16 h = __float2bfloat16(f);
    return *reinterpret_cast<short*>(&h);
}
__device__ __forceinline__ float bf2f(short s) {
    unsigned int u = ((unsigned int)(unsigned short)s) << 16;
    union { unsigned int u; float f; } c; c.u = u;
    return c.f;
}

// async global->LDS, 16 B per lane; LDS dest = wave-uniform base + lane*16
__device__ __forceinline__ void gload_lds16(const void* g, void* l) {
    __builtin_amdgcn_global_load_lds(
        (const __attribute__((address_space(1))) unsigned int*)g,
        (__attribute__((address_space(3))) unsigned int*)l, 16, 0, 0);
}

// ---------------------------------------------------------------------------
// f32 -> bf16 conversion (vectorized: 8 elems / thread)
// ---------------------------------------------------------------------------
__global__ __launch_bounds__(256)
void cvt_bf16_kernel(const float* __restrict__ in, short* __restrict__ out, int n8)
{
    int i = blockIdx.x * 256 + threadIdx.x;
    if (i >= n8) return;
    float4 a = *reinterpret_cast<const float4*>(&in[i*8]);
    float4 b = *reinterpret_cast<const float4*>(&in[i*8+4]);
    bf16x8 o;
    o[0]=f2bf(a.x); o[1]=f2bf(a.y); o[2]=f2bf(a.z); o[3]=f2bf(a.w);
    o[4]=f2bf(b.x); o[5]=f2bf(b.y); o[6]=f2bf(b.z); o[7]=f2bf(b.w);
    *reinterpret_cast<bf16x8*>(&out[i*8]) = o;
}

// ---------------------------------------------------------------------------
// bf16 MFMA GEMM (unchanged from round 5 — verified): C = A@B^T + bias.
// 128x128 tile, BK=32, 4 waves (2x2), 4x4 16x16x32 frags, global_load_lds.
// ---------------------------------------------------------------------------
__device__ __forceinline__ void store_val(float v, float* p) { *p = v; }
__device__ __forceinline__ void store_val(float v, short* p) { *p = f2bf(v); }

template<typename OT>
__global__ __launch_bounds__(256)
void gemm_bf16_nt(const short* __restrict__ A, int lda,
                  const short* __restrict__ B,
                  const float* __restrict__ bias, OT* __restrict__ C,
                  int M, int N, int K)
{
    __shared__ short As[128][32];
    __shared__ short Bs[128][32];

    const int tid = threadIdx.x;
    const int w   = tid >> 6;
    const int l   = tid & 63;
    const int l15 = l & 15;
    const int l4  = l >> 4;
    const int wr  = w >> 1;
    const int wc  = w & 1;
    const int row0 = blockIdx.y * 128;
    const int col0 = blockIdx.x * 128;

    const int srow = l >> 2;
    const int sk   = (l & 3) * 8;

    f32x4 acc[4][4];
    #pragma unroll
    for (int mi = 0; mi < 4; ++mi)
        #pragma unroll
        for (int ni = 0; ni < 4; ++ni) acc[mi][ni] = (f32x4){0.f,0.f,0.f,0.f};

    for (int k0 = 0; k0 < K; k0 += 32) {
        {
            const int c0 = w, c1 = w + 4;
            gload_lds16(&A[(size_t)(row0 + c0*16 + srow) * lda + k0 + sk], &As[c0*16][0]);
            gload_lds16(&A[(size_t)(row0 + c1*16 + srow) * lda + k0 + sk], &As[c1*16][0]);
            gload_lds16(&B[(size_t)(col0 + c0*16 + srow) * K   + k0 + sk], &Bs[c0*16][0]);
            gload_lds16(&B[(size_t)(col0 + c1*16 + srow) * K   + k0 + sk], &Bs[c1*16][0]);
        }
        __syncthreads();

        bf16x8 af[4], bfr[4];
        #pragma unroll
        for (int mi = 0; mi < 4; ++mi)
            af[mi] = *reinterpret_cast<const bf16x8*>(&As[wr*64 + mi*16 + l15][l4*8]);
        #pragma unroll
        for (int ni = 0; ni < 4; ++ni)
            bfr[ni] = *reinterpret_cast<const bf16x8*>(&Bs[wc*64 + ni*16 + l15][l4*8]);

        #pragma unroll
        for (int mi = 0; mi < 4; ++mi)
            #pragma unroll
            for (int ni = 0; ni < 4; ++ni)
                acc[mi][ni] = __builtin_amdgcn_mfma_f32_16x16x32_bf16(
                    af[mi], bfr[ni], acc[mi][ni], 0, 0, 0);
        __syncthreads();
    }

    #pragma unroll
    for (int ni = 0; ni < 4; ++ni) {
        int col = col0 + wc*64 + ni*16 + l15;
        float bv = bias[col];
        #pragma unroll
        for (int mi = 0; mi < 4; ++mi) {
            #pragma unroll
            for (int r = 0; r < 4; ++r) {
                size_t row = (size_t)(row0 + wr*64 + mi*16 + l4*4 + r);
                store_val(acc[mi][ni][r] + bv, &C[row * (size_t)N + col]);
            }
        }
    }
}

// ---------------------------------------------------------------------------
// RoPE in-place on bf16 q,k slices (unchanged from round 5).
// ---------------------------------------------------------------------------
__global__ __launch_bounds__(256)
void rope_bf16_kernel(short* __restrict__ qkv, const float* __restrict__ rpe)
{
    int idx = blockIdx.x * 256 + threadIdx.x;
    int blk = idx % 5;
    int h   = (idx / 5) % NHEAD;
    int s   = (idx / (5*NHEAD)) % SEQ;
    int t   = idx / (5*NHEAD*SEQ);
    int d0  = blk * 8;

    const float* rp = rpe + s*40 + d0;
    short* p = qkv + (size_t)s*QKVN + t*EMB + h*HDIM + d0;
    bf16x8 v0 = *reinterpret_cast<const bf16x8*>(p);
    bf16x8 v1 = *reinterpret_cast<const bf16x8*>(p + 40);
    bf16x8 o0, o1;
    #pragma unroll
    for (int j = 0; j < 8; ++j) {
        float ang = rp[j];
        float sn = sinf(ang), cs = cosf(ang);
        float a = bf2f(v0[j]), b = bf2f(v1[j]);
        o0[j] = f2bf(a*cs - b*sn);
        o1[j] = f2bf(b*cs + a*sn);
    }
    *reinterpret_cast<bf16x8*>(p)      = o0;
    *reinterpret_cast<bf16x8*>(p + 40) = o1;
}

// ---------------------------------------------------------------------------
// MFMA flash attention, round 6 restructure.
// Block = 4 waves = 64 q rows of one (head, seg); wave owns 16 q-rows.
//
// QK^T computed SWAPPED: S^T = mfma(A=K-frag, B=Q-frag). Same LDS reads and
// Q registers as round 5 (verified); D-frag gives col=l15=qrow, row=key.
// => softmax state (m, lsum) is ONE SCALAR PER LANE; reduction over keys =
// 16 in-register values + shfl_xor(16,32). corr/normalize need no shuffles.
//
// PV uses the k-slot relabeling freedom of MFMA: with the verified x32
// layout (lane group l4 holds k-slots 8*l4..8*l4+7), assign slot (l4,j) the
// key 32s + 16*(j>>2) + 4*l4 + (j&3). Then the B-frag (P^T) is built from
// the lane's OWN p registers (no LDS, no shuffles), and the A-frag (V^T)
// is two ds_read_b64 from the swizzled Vt tile. O accumulates transposed
// (row=d, col=qrow), so per-lane softmax scalars apply directly.
//
// K/V global loads for chunk t+1 are issued into registers right after the
// LDS writes of chunk t (T14 async-stage split) to hide HBM/L2 latency.
// Segments are multiples of 64 (cu = k*1024), no tail masking needed.
// ---------------------------------------------------------------------------
__global__ __launch_bounds__(256)
void attn_mfma(const short* __restrict__ qkv, const int* __restrict__ cu,
               short* __restrict__ aout)
{
    const int h   = blockIdx.z;
    const int seg = blockIdx.y;
    const int qt  = blockIdx.x;
    const int s0 = cu[seg], s1 = cu[seg+1];

    const int tid = threadIdx.x;
    const int w   = tid >> 6;
    const int l   = tid & 63;
    const int l15 = l & 15;
    const int l4  = l >> 4;

    __shared__ short Kl[64][128];    // 16 KB: K rows, XOR-swizzled 8-elem units
    __shared__ short Vt[HDIM][64];   // 10 KB: V^T, swizzled units

    const int q0 = s0 + qt*64 + w*16;

    bf16x8 bzero;
    #pragma unroll
    for (int j = 0; j < 8; ++j) bzero[j] = 0;

    // Q fragments (B-operand): col=l15=qrow, k=l4*8+j = d (padded 80->96)
    bf16x8 qf[3];
    {
        const short* qp = qkv + (size_t)(q0 + l15) * QKVN + h*HDIM;
        qf[0] = *reinterpret_cast<const bf16x8*>(qp + l4*8);
        qf[1] = *reinterpret_cast<const bf16x8*>(qp + 32 + l4*8);
        qf[2] = (l4 < 2) ? *reinterpret_cast<const bf16x8*>(qp + 64 + l4*8) : bzero;
    }

    // per-lane softmax state (this lane's q-row = q0 + l15)
    float m = -3.4e38f, lsum = 0.f;
    f32x4 O[5];   // O^T: lane holds d = dt*16 + 4*l4 + r, qrow = l15
    #pragma unroll
    for (int dt = 0; dt < 5; ++dt) O[dt] = (f32x4){0.f,0.f,0.f,0.f};

    // ---- per-thread staging geometry (constants across chunks) ----
    // K: 3 tasks (64 rows x 12 units; units 10,11 zero-pad)
    int kkey[3], ku[3];
    const short* kptr[3];
    short* klds[3];
    #pragma unroll
    for (int i = 0; i < 3; ++i) {
        int task = tid + i*256;
        kkey[i] = task / 12;
        ku[i]   = task - kkey[i]*12;
        kptr[i] = qkv + (size_t)(s0 + kkey[i])*QKVN + EMB + h*HDIM + ku[i]*8;
        klds[i] = &Kl[kkey[i]][(ku[i] ^ (kkey[i] & 7))*8];
    }
    // V: 5 tasks (64 k x 20 d-quads), transposed+swizzled scatter indices
    int vIdx[5][4];
    const short* vptr[5];
    #pragma unroll
    for (int i = 0; i < 5; ++i) {
        int task = tid + i*256;
        int k  = task / 20;
        int dq = task - k*20;
        vptr[i] = qkv + (size_t)(s0 + k)*QKVN + 2*EMB + h*HDIM + dq*4;
        #pragma unroll
        for (int c = 0; c < 4; ++c) {
            int d = dq*4 + c;
            vIdx[i][c] = d*64 + (((k>>3) ^ (d & 7))*8) + (k & 7);
        }
    }

    // ---- preload chunk 0 into registers ----
    bf16x8 kreg[3];
    bf16x4 vreg[5];
    #pragma unroll
    for (int i = 0; i < 3; ++i)
        kreg[i] = (ku[i] < 10) ? *reinterpret_cast<const bf16x8*>(kptr[i]) : bzero;
    #pragma unroll
    for (int i = 0; i < 5; ++i)
        vreg[i] = *reinterpret_cast<const bf16x4*>(vptr[i]);

    const float scale = 0.11180339887498948f;   // 1/sqrt(80)
    const int nk = s1 - s0;
    const size_t step = (size_t)64 * QKVN;
    short* vt_flat = &Vt[0][0];

    for (int kc = 0; kc < nk; kc += 64) {
        __syncthreads();   // previous chunk's LDS reads complete

        // ---- write staged registers to LDS ----
        #pragma unroll
        for (int i = 0; i < 3; ++i)
            *reinterpret_cast<bf16x8*>(klds[i]) = kreg[i];
        #pragma unroll
        for (int i = 0; i < 5; ++i) {
            vt_flat[vIdx[i][0]] = vreg[i][0];
            vt_flat[vIdx[i][1]] = vreg[i][1];
            vt_flat[vIdx[i][2]] = vreg[i][2];
            vt_flat[vIdx[i][3]] = vreg[i][3];
        }

        // ---- issue next chunk's global loads (overlap with compute) ----
        if (kc + 64 < nk) {
            #pragma unroll
            for (int i = 0; i < 3; ++i) {
                kptr[i] += step;
                if (ku[i] < 10) kreg[i] = *reinterpret_cast<const bf16x8*>(kptr[i]);
            }
            #pragma unroll
            for (int i = 0; i < 5; ++i) {
                vptr[i] += step;
                vreg[i] = *reinterpret_cast<const bf16x4*>(vptr[i]);
            }
        }
        __syncthreads();   // staged LDS visible to all waves

        // ---- S^T = K Q : 4 key-tiles x 3 k-steps (swapped operands) ----
        f32x4 S[4];
        #pragma unroll
        for (int ct = 0; ct < 4; ++ct) {
            f32x4 acc = (f32x4){0.f,0.f,0.f,0.f};
            int key = ct*16 + l15;   // A-frag row
            #pragma unroll
            for (int t = 0; t < 3; ++t) {
                int u = (4*t + l4) ^ (key & 7);
                bf16x8 a = *reinterpret_cast<const bf16x8*>(&Kl[key][u*8]);
                acc = __builtin_amdgcn_mfma_f32_16x16x32_bf16(a, qf[t], acc, 0, 0, 0);
            }
            S[ct] = acc;   // S[ct][r] = S^T[key=16ct+4*l4+r][qrow=l15]
        }

        // ---- per-lane online softmax over 64 keys ----
        float mx = -3.4e38f;
        #pragma unroll
        for (int ct = 0; ct < 4; ++ct)
            #pragma unroll
            for (int r = 0; r < 4; ++r) {
                float v = S[ct][r] * scale;
                S[ct][r] = v;
                mx = fmaxf(mx, v);
            }
        mx = fmaxf(mx, __shfl_xor(mx, 16));
        mx = fmaxf(mx, __shfl_xor(mx, 32));
        float mn   = fmaxf(m, mx);
        float corr = __expf(m - mn);
        float p[4][4];
        float ps = 0.f;
        #pragma unroll
        for (int ct = 0; ct < 4; ++ct)
            #pragma unroll
            for (int r = 0; r < 4; ++r) {
                float e = __expf(S[ct][r] - mn);
                p[ct][r] = e;
                ps += e;
            }
        ps += __shfl_xor(ps, 16);
        ps += __shfl_xor(ps, 32);
        lsum = lsum * corr + ps;
        m = mn;
        #pragma unroll
        for (int dt = 0; dt < 5; ++dt)
            #pragma unroll
            for (int r = 0; r < 4; ++r) O[dt][r] *= corr;

        // ---- O^T += V^T P^T : 2 k-steps, k-slot (l4,j) <-> key
        //      32s + 16*(j>>2) + 4*l4 + (j&3); B-frag fully lane-local ----
        const int off = 4*(l4 & 1);
        #pragma unroll
        for (int s = 0; s < 2; ++s) {
            bf16x8 pb;
            #pragma unroll
            for (int j = 0; j < 8; ++j)
                pb[j] = f2bf(p[2*s + (j>>2)][j & 3]);
            int ulo = 4*s + (l4 >> 1);
            #pragma unroll
            for (int dt = 0; dt < 5; ++dt) {
                int d = dt*16 + l15;
                bf16x4 lo = *reinterpret_cast<const bf16x4*>(
                    &Vt[d][((ulo       ^ (d & 7))*8) + off]);
                bf16x4 hi = *reinterpret_cast<const bf16x4*>(
                    &Vt[d][(((ulo + 2) ^ (d & 7))*8) + off]);
                bf16x8 va = __builtin_shufflevector(lo, hi, 0,1,2,3,4,5,6,7);
                O[dt] = __builtin_amdgcn_mfma_f32_16x16x32_bf16(va, pb, O[dt], 0, 0, 0);
            }
        }
    }

    // ---- normalize (per-lane scalar), write O^T as packed 8 B stores ----
    float inv = 1.f / lsum;
    short* orow = aout + (size_t)(q0 + l15) * EMB + h*HDIM;
    #pragma unroll
    for (int dt = 0; dt < 5; ++dt) {
        bf16x4 o4;
        #pragma unroll
        for (int r = 0; r < 4; ++r) o4[r] = f2bf(O[dt][r] * inv);
        *reinterpret_cast<bf16x4*>(&orow[dt*16 + 4*l4]) = o4;
    }
}

// ---------------------------------------------------------------------------
extern "C" void kernel_launch(void* const* d_in, const int* in_sizes, int n_in,
                              void* d_out, int out_size, void* d_ws, size_t ws_size,
                              hipStream_t stream)
{
    const float* x      = (const float*)d_in[0];
    const float* rpe    = (const float*)d_in[1];
    const float* qkv_w  = (const float*)d_in[2];
    const float* qkv_b  = (const float*)d_in[3];
    const float* proj_w = (const float*)d_in[4];
    const float* proj_b = (const float*)d_in[5];
    const int*   cu     = (const int*)d_in[6];
    float* out = (float*)d_out;

    short* ws       = (short*)d_ws;
    short* qkv_bf   = ws;                                   // SEQ*QKVN
    short* x_bf     = qkv_bf  + (size_t)SEQ * QKVN;         // SEQ*EMB
    short* qkvw_bf  = x_bf    + (size_t)SEQ * EMB;          // QKVN*EMB
    short* projw_bf = qkvw_bf + (size_t)QKVN * EMB;         // EMB*EMB
    short* attn_bf  = projw_bf+ (size_t)EMB * EMB;          // SEQ*EMB

    dim3 blk(256);

    // 0) convert inputs to bf16
    cvt_bf16_kernel<<<dim3(SEQ*EMB/8/256),  blk, 0, stream>>>(x,      x_bf,     SEQ*EMB/8);
    cvt_bf16_kernel<<<dim3(QKVN*EMB/8/256), blk, 0, stream>>>(qkv_w,  qkvw_bf,  QKVN*EMB/8);
    cvt_bf16_kernel<<<dim3(EMB*EMB/8/256),  blk, 0, stream>>>(proj_w, projw_bf, EMB*EMB/8);

    // 1) qkv = x @ qkv_w^T + qkv_b  (bf16 out)
    gemm_bf16_nt<short><<<dim3(QKVN/128, SEQ/128), blk, 0, stream>>>(
        x_bf, EMB, qkvw_bf, qkv_b, qkv_bf, SEQ, QKVN, EMB);

    // 2) RoPE in-place on bf16 q,k
    rope_bf16_kernel<<<dim3(2*SEQ*NHEAD*5/256), blk, 0, stream>>>(qkv_bf, rpe);

    // 3) block-diagonal MFMA attention -> bf16 planar attn_bf
    attn_mfma<<<dim3((SEQ/NSEGS)/64, NSEGS, NHEAD), blk, 0, stream>>>(
        qkv_bf, cu, attn_bf);

    // 4) out = attn @ proj_w^T + proj_b (f32 out)
    gemm_bf16_nt<float><<<dim3(EMB/128, SEQ/128), blk, 0, stream>>>(
        attn_bf, EMB, projw_bf, proj_b, out, SEQ, EMB, EMB);
}

// Round 7
// 158.564 us; speedup vs baseline: 9.0428x; 1.1286x over previous
//
#include <hip/hip_runtime.h>
#include <hip/hip_bf16.h>
#include <math.h>

// Problem constants (fixed by reference)
#define SEQ   3072
#define EMB   1280
#define NHEAD 16
#define HDIM  80
#define QKVN  3840   // 3*EMB
#define NSEGS 3

typedef __attribute__((ext_vector_type(8))) short bf16x8;  // 8 bf16 (4 VGPRs)
typedef __attribute__((ext_vector_type(4))) short bf16x4;  // 4 bf16 (8 B)
typedef __attribute__((ext_vector_type(4))) float f32x4;   // MFMA C/D frag

__device__ __forceinline__ short f2bf(float f) {
    __hip_bfloat16 h = __float2bfloat16(f);
    return *reinterpret_cast<short*>(&h);
}
__device__ __forceinline__ float bf2f(short s) {
    unsigned int u = ((unsigned int)(unsigned short)s) << 16;
    union { unsigned int u; float f; } c; c.u = u;
    return c.f;
}

// async global->LDS, 16 B per lane; LDS dest = wave-uniform base + lane*16
__device__ __forceinline__ void gload_lds16(const void* g, void* l) {
    __builtin_amdgcn_global_load_lds(
        (const __attribute__((address_space(1))) unsigned int*)g,
        (__attribute__((address_space(3))) unsigned int*)l, 16, 0, 0);
}

// ---------------------------------------------------------------------------
// f32 -> bf16 conversion (vectorized: 8 elems / thread)
// ---------------------------------------------------------------------------
__global__ __launch_bounds__(256)
void cvt_bf16_kernel(const float* __restrict__ in, short* __restrict__ out, int n8)
{
    int i = blockIdx.x * 256 + threadIdx.x;
    if (i >= n8) return;
    float4 a = *reinterpret_cast<const float4*>(&in[i*8]);
    float4 b = *reinterpret_cast<const float4*>(&in[i*8+4]);
    bf16x8 o;
    o[0]=f2bf(a.x); o[1]=f2bf(a.y); o[2]=f2bf(a.z); o[3]=f2bf(a.w);
    o[4]=f2bf(b.x); o[5]=f2bf(b.y); o[6]=f2bf(b.z); o[7]=f2bf(b.w);
    *reinterpret_cast<bf16x8*>(&out[i*8]) = o;
}

// ---------------------------------------------------------------------------
// bf16 MFMA GEMM (unchanged — verified): C = A@B^T + bias.
// 128x128 tile, BK=32, 4 waves (2x2), 4x4 16x16x32 frags, global_load_lds.
// ---------------------------------------------------------------------------
__device__ __forceinline__ void store_val(float v, float* p) { *p = v; }
__device__ __forceinline__ void store_val(float v, short* p) { *p = f2bf(v); }

template<typename OT>
__global__ __launch_bounds__(256)
void gemm_bf16_nt(const short* __restrict__ A, int lda,
                  const short* __restrict__ B,
                  const float* __restrict__ bias, OT* __restrict__ C,
                  int M, int N, int K)
{
    __shared__ short As[128][32];
    __shared__ short Bs[128][32];

    const int tid = threadIdx.x;
    const int w   = tid >> 6;
    const int l   = tid & 63;
    const int l15 = l & 15;
    const int l4  = l >> 4;
    const int wr  = w >> 1;
    const int wc  = w & 1;
    const int row0 = blockIdx.y * 128;
    const int col0 = blockIdx.x * 128;

    const int srow = l >> 2;
    const int sk   = (l & 3) * 8;

    f32x4 acc[4][4];
    #pragma unroll
    for (int mi = 0; mi < 4; ++mi)
        #pragma unroll
        for (int ni = 0; ni < 4; ++ni) acc[mi][ni] = (f32x4){0.f,0.f,0.f,0.f};

    for (int k0 = 0; k0 < K; k0 += 32) {
        {
            const int c0 = w, c1 = w + 4;
            gload_lds16(&A[(size_t)(row0 + c0*16 + srow) * lda + k0 + sk], &As[c0*16][0]);
            gload_lds16(&A[(size_t)(row0 + c1*16 + srow) * lda + k0 + sk], &As[c1*16][0]);
            gload_lds16(&B[(size_t)(col0 + c0*16 + srow) * K   + k0 + sk], &Bs[c0*16][0]);
            gload_lds16(&B[(size_t)(col0 + c1*16 + srow) * K   + k0 + sk], &Bs[c1*16][0]);
        }
        __syncthreads();

        bf16x8 af[4], bfr[4];
        #pragma unroll
        for (int mi = 0; mi < 4; ++mi)
            af[mi] = *reinterpret_cast<const bf16x8*>(&As[wr*64 + mi*16 + l15][l4*8]);
        #pragma unroll
        for (int ni = 0; ni < 4; ++ni)
            bfr[ni] = *reinterpret_cast<const bf16x8*>(&Bs[wc*64 + ni*16 + l15][l4*8]);

        #pragma unroll
        for (int mi = 0; mi < 4; ++mi)
            #pragma unroll
            for (int ni = 0; ni < 4; ++ni)
                acc[mi][ni] = __builtin_amdgcn_mfma_f32_16x16x32_bf16(
                    af[mi], bfr[ni], acc[mi][ni], 0, 0, 0);
        __syncthreads();
    }

    #pragma unroll
    for (int ni = 0; ni < 4; ++ni) {
        int col = col0 + wc*64 + ni*16 + l15;
        float bv = bias[col];
        #pragma unroll
        for (int mi = 0; mi < 4; ++mi) {
            #pragma unroll
            for (int r = 0; r < 4; ++r) {
                size_t row = (size_t)(row0 + wr*64 + mi*16 + l4*4 + r);
                store_val(acc[mi][ni][r] + bv, &C[row * (size_t)N + col]);
            }
        }
    }
}

// ---------------------------------------------------------------------------
// RoPE in-place on bf16 q,k slices (unchanged).
// ---------------------------------------------------------------------------
__global__ __launch_bounds__(256)
void rope_bf16_kernel(short* __restrict__ qkv, const float* __restrict__ rpe)
{
    int idx = blockIdx.x * 256 + threadIdx.x;
    int blk = idx % 5;
    int h   = (idx / 5) % NHEAD;
    int s   = (idx / (5*NHEAD)) % SEQ;
    int t   = idx / (5*NHEAD*SEQ);
    int d0  = blk * 8;

    const float* rp = rpe + s*40 + d0;
    short* p = qkv + (size_t)s*QKVN + t*EMB + h*HDIM + d0;
    bf16x8 v0 = *reinterpret_cast<const bf16x8*>(p);
    bf16x8 v1 = *reinterpret_cast<const bf16x8*>(p + 40);
    bf16x8 o0, o1;
    #pragma unroll
    for (int j = 0; j < 8; ++j) {
        float ang = rp[j];
        float sn = sinf(ang), cs = cosf(ang);
        float a = bf2f(v0[j]), b = bf2f(v1[j]);
        o0[j] = f2bf(a*cs - b*sn);
        o1[j] = f2bf(b*cs + a*sn);
    }
    *reinterpret_cast<bf16x8*>(p)      = o0;
    *reinterpret_cast<bf16x8*>(p + 40) = o1;
}

// ---------------------------------------------------------------------------
// MFMA flash attention, round 7: conflict-free V path.
//
// Same verified algebra as round 6 (swapped QK^T -> per-lane softmax; PV with
// slot (l4,j) <-> key = 32s + 16*(j>>2) + 4*l4 + (j&3); O^T accumulation).
//
// NEW V^T LDS layout Vt[d][64] with key-QUAD PERMUTATION + XOR swizzle:
//   key k -> unit u = ((k>>2)&3)|((k>>5)<<2), sub b=(k>>4)&1, pos = b*4+(k&3)
//   element addr (shorts) = d*64 + ((u ^ (d&7))*8) + pos
// This puts each lane's two key-quads (8s+l4, 8s+4+l4) in ONE 16-B granule ->
// PV A-frag = single ds_read_b128, 8 lanes/granule = throughput-minimal.
// Staging: thread owns one k (=lane) x 16 consecutive d -> per store instr
// all lanes share d and spread u over all 8 granules -> 2-way = free.
// Softmax in exp2 domain (log2e folded into scale). setprio(1) around MFMAs.
// ---------------------------------------------------------------------------
__global__ __launch_bounds__(256)
void attn_mfma(const short* __restrict__ qkv, const int* __restrict__ cu,
               short* __restrict__ aout)
{
    const int h   = blockIdx.z;
    const int seg = blockIdx.y;
    const int qt  = blockIdx.x;
    const int s0 = cu[seg], s1 = cu[seg+1];

    const int tid = threadIdx.x;
    const int w   = tid >> 6;
    const int l   = tid & 63;
    const int l15 = l & 15;
    const int l4  = l >> 4;

    __shared__ short Kl[64][128];    // 16 KB: K rows, XOR-swizzled 8-elem units
    __shared__ short Vt[HDIM][64];   // 10 KB: V^T, quad-permuted + swizzled

    const int q0 = s0 + qt*64 + w*16;

    bf16x8 bzero;
    #pragma unroll
    for (int j = 0; j < 8; ++j) bzero[j] = 0;

    // Q fragments (B-operand): col=l15=qrow, k=l4*8+j = d (padded 80->96)
    bf16x8 qf[3];
    {
        const short* qp = qkv + (size_t)(q0 + l15) * QKVN + h*HDIM;
        qf[0] = *reinterpret_cast<const bf16x8*>(qp + l4*8);
        qf[1] = *reinterpret_cast<const bf16x8*>(qp + 32 + l4*8);
        qf[2] = (l4 < 2) ? *reinterpret_cast<const bf16x8*>(qp + 64 + l4*8) : bzero;
    }

    // per-lane softmax state (exp2 domain), q-row = q0 + l15
    float m = -3.4e38f, lsum = 0.f;
    f32x4 O[5];   // O^T: lane holds d = dt*16 + 4*l4 + r, qrow = l15
    #pragma unroll
    for (int dt = 0; dt < 5; ++dt) O[dt] = (f32x4){0.f,0.f,0.f,0.f};

    // ---- K staging geometry (unchanged from round 6) ----
    int kkey[3], ku[3];
    const short* kptr[3];
    short* klds[3];
    #pragma unroll
    for (int i = 0; i < 3; ++i) {
        int task = tid + i*256;
        kkey[i] = task / 12;
        ku[i]   = task - kkey[i]*12;
        kptr[i] = qkv + (size_t)(s0 + kkey[i])*QKVN + EMB + h*HDIM + ku[i]*8;
        klds[i] = &Kl[kkey[i]][(ku[i] ^ (kkey[i] & 7))*8];
    }

    // ---- V staging geometry: primary task k=l, d in [w*16, w*16+16);
    //      secondary (l<16) k=w*16+l, d in [64,80) ----
    const int u1  = ((l >> 2) & 3) | ((l >> 5) << 2);
    const int bs1 = ((l >> 4) & 1) * 4 + (l & 3);
    const int k2  = w*16 + l15;                   // secondary k (l<16 only)
    const int u2  = ((k2 >> 2) & 3) | ((k2 >> 5) << 2);
    const int bs2 = ((k2 >> 4) & 1) * 4 + (k2 & 3);
    const bool sec = (l < 16);

    const short* vp1 = qkv + (size_t)(s0 + l)  * QKVN + 2*EMB + h*HDIM + w*16;
    const short* vp2 = qkv + (size_t)(s0 + k2) * QKVN + 2*EMB + h*HDIM + 64;

    // ---- preload chunk 0 ----
    bf16x8 kreg[3];
    bf16x8 vregA, vregB, vregC, vregD;
    #pragma unroll
    for (int i = 0; i < 3; ++i)
        kreg[i] = (ku[i] < 10) ? *reinterpret_cast<const bf16x8*>(kptr[i]) : bzero;
    vregA = *reinterpret_cast<const bf16x8*>(vp1);
    vregB = *reinterpret_cast<const bf16x8*>(vp1 + 8);
    if (sec) {
        vregC = *reinterpret_cast<const bf16x8*>(vp2);
        vregD = *reinterpret_cast<const bf16x8*>(vp2 + 8);
    }

    const float scale2 = 0.1612982054f;   // log2(e)/sqrt(80)
    const int nk = s1 - s0;
    const size_t step = (size_t)64 * QKVN;
    short* vt_flat = &Vt[0][0];

    for (int kc = 0; kc < nk; kc += 64) {
        __syncthreads();   // previous chunk's LDS reads complete

        // ---- write staged registers to LDS ----
        #pragma unroll
        for (int i = 0; i < 3; ++i)
            *reinterpret_cast<bf16x8*>(klds[i]) = kreg[i];
        {
            const int rb = w*16*64;
            #pragma unroll
            for (int i = 0; i < 8; ++i) {
                vt_flat[rb + i*64      + ((u1 ^ i)       & 7)*8 + bs1] = vregA[i];
                vt_flat[rb + (i+8)*64  + ((u1 ^ i)       & 7)*8 + bs1] = vregB[i];
            }
            if (sec) {
                #pragma unroll
                for (int i = 0; i < 8; ++i) {
                    vt_flat[(64+i)*64  + ((u2 ^ i)       & 7)*8 + bs2] = vregC[i];
                    vt_flat[(72+i)*64  + ((u2 ^ i)       & 7)*8 + bs2] = vregD[i];
                }
            }
        }

        // ---- issue next chunk's global loads (overlap with compute) ----
        if (kc + 64 < nk) {
            #pragma unroll
            for (int i = 0; i < 3; ++i) {
                kptr[i] += step;
                if (ku[i] < 10) kreg[i] = *reinterpret_cast<const bf16x8*>(kptr[i]);
            }
            vp1 += step; vp2 += step;
            vregA = *reinterpret_cast<const bf16x8*>(vp1);
            vregB = *reinterpret_cast<const bf16x8*>(vp1 + 8);
            if (sec) {
                vregC = *reinterpret_cast<const bf16x8*>(vp2);
                vregD = *reinterpret_cast<const bf16x8*>(vp2 + 8);
            }
        }
        __syncthreads();   // staged LDS visible to all waves

        // ---- S^T = K Q : 4 key-tiles x 3 k-steps (swapped operands) ----
        f32x4 S[4];
        __builtin_amdgcn_s_setprio(1);
        #pragma unroll
        for (int ct = 0; ct < 4; ++ct) {
            f32x4 acc = (f32x4){0.f,0.f,0.f,0.f};
            int key = ct*16 + l15;
            #pragma unroll
            for (int t = 0; t < 3; ++t) {
                int u = (4*t + l4) ^ (key & 7);
                bf16x8 a = *reinterpret_cast<const bf16x8*>(&Kl[key][u*8]);
                acc = __builtin_amdgcn_mfma_f32_16x16x32_bf16(a, qf[t], acc, 0, 0, 0);
            }
            S[ct] = acc;   // S[ct][r] = S^T[key=16ct+4*l4+r][qrow=l15]
        }
        __builtin_amdgcn_s_setprio(0);

        // ---- per-lane online softmax (exp2 domain) over 64 keys ----
        float mx = -3.4e38f;
        #pragma unroll
        for (int ct = 0; ct < 4; ++ct)
            #pragma unroll
            for (int r = 0; r < 4; ++r) {
                float v = S[ct][r] * scale2;
                S[ct][r] = v;
                mx = fmaxf(mx, v);
            }
        mx = fmaxf(mx, __shfl_xor(mx, 16));
        mx = fmaxf(mx, __shfl_xor(mx, 32));
        float mn   = fmaxf(m, mx);
        float corr = exp2f(m - mn);
        float p[4][4];
        float ps = 0.f;
        #pragma unroll
        for (int ct = 0; ct < 4; ++ct)
            #pragma unroll
            for (int r = 0; r < 4; ++r) {
                float e = exp2f(S[ct][r] - mn);
                p[ct][r] = e;
                ps += e;
            }
        ps += __shfl_xor(ps, 16);
        ps += __shfl_xor(ps, 32);
        lsum = lsum * corr + ps;
        m = mn;
        #pragma unroll
        for (int dt = 0; dt < 5; ++dt)
            #pragma unroll
            for (int r = 0; r < 4; ++r) O[dt][r] *= corr;

        // ---- O^T += V^T P^T : per s-half one b128 A-frag read per d-tile ----
        #pragma unroll
        for (int s2 = 0; s2 < 2; ++s2) {
            bf16x8 pb;
            #pragma unroll
            for (int j = 0; j < 8; ++j)
                pb[j] = f2bf(p[2*s2 + (j>>2)][j & 3]);
            __builtin_amdgcn_s_setprio(1);
            #pragma unroll
            for (int dt = 0; dt < 5; ++dt) {
                int d = dt*16 + l15;
                bf16x8 va = *reinterpret_cast<const bf16x8*>(
                    &vt_flat[d*64 + (((4*s2 + l4) ^ (d & 7)) & 7)*8]);
                O[dt] = __builtin_amdgcn_mfma_f32_16x16x32_bf16(va, pb, O[dt], 0, 0, 0);
            }
            __builtin_amdgcn_s_setprio(0);
        }
    }

    // ---- normalize (per-lane scalar), write O^T as packed 8 B stores ----
    float inv = 1.f / lsum;
    short* orow = aout + (size_t)(q0 + l15) * EMB + h*HDIM;
    #pragma unroll
    for (int dt = 0; dt < 5; ++dt) {
        bf16x4 o4;
        #pragma unroll
        for (int r = 0; r < 4; ++r) o4[r] = f2bf(O[dt][r] * inv);
        *reinterpret_cast<bf16x4*>(&orow[dt*16 + 4*l4]) = o4;
    }
}

// ---------------------------------------------------------------------------
extern "C" void kernel_launch(void* const* d_in, const int* in_sizes, int n_in,
                              void* d_out, int out_size, void* d_ws, size_t ws_size,
                              hipStream_t stream)
{
    const float* x      = (const float*)d_in[0];
    const float* rpe    = (const float*)d_in[1];
    const float* qkv_w  = (const float*)d_in[2];
    const float* qkv_b  = (const float*)d_in[3];
    const float* proj_w = (const float*)d_in[4];
    const float* proj_b = (const float*)d_in[5];
    const int*   cu     = (const int*)d_in[6];
    float* out = (float*)d_out;

    short* ws       = (short*)d_ws;
    short* qkv_bf   = ws;                                   // SEQ*QKVN
    short* x_bf     = qkv_bf  + (size_t)SEQ * QKVN;         // SEQ*EMB
    short* qkvw_bf  = x_bf    + (size_t)SEQ * EMB;          // QKVN*EMB
    short* projw_bf = qkvw_bf + (size_t)QKVN * EMB;         // EMB*EMB
    short* attn_bf  = projw_bf+ (size_t)EMB * EMB;          // SEQ*EMB

    dim3 blk(256);

    // 0) convert inputs to bf16
    cvt_bf16_kernel<<<dim3(SEQ*EMB/8/256),  blk, 0, stream>>>(x,      x_bf,     SEQ*EMB/8);
    cvt_bf16_kernel<<<dim3(QKVN*EMB/8/256), blk, 0, stream>>>(qkv_w,  qkvw_bf,  QKVN*EMB/8);
    cvt_bf16_kernel<<<dim3(EMB*EMB/8/256),  blk, 0, stream>>>(proj_w, projw_bf, EMB*EMB/8);

    // 1) qkv = x @ qkv_w^T + qkv_b  (bf16 out)
    gemm_bf16_nt<short><<<dim3(QKVN/128, SEQ/128), blk, 0, stream>>>(
        x_bf, EMB, qkvw_bf, qkv_b, qkv_bf, SEQ, QKVN, EMB);

    // 2) RoPE in-place on bf16 q,k
    rope_bf16_kernel<<<dim3(2*SEQ*NHEAD*5/256), blk, 0, stream>>>(qkv_bf, rpe);

    // 3) block-diagonal MFMA attention -> bf16 planar attn_bf
    attn_mfma<<<dim3((SEQ/NSEGS)/64, NSEGS, NHEAD), blk, 0, stream>>>(
        qkv_bf, cu, attn_bf);

    // 4) out = attn @ proj_w^T + proj_b (f32 out)
    gemm_bf16_nt<float><<<dim3(EMB/128, SEQ/128), blk, 0, stream>>>(
        attn_bf, EMB, projw_bf, proj_b, out, SEQ, EMB, EMB);
}